// Round 16
// baseline (416.365 us; speedup 1.0000x reference)
//
#include <hip/hip_runtime.h>
#include <stdint.h>

#define TL  2048
#define NB  4096
#define INSZ 8
#define HID 10
#define LOG2E 1.4426950408889634f
#define XS (NB * INSZ)            // floats per timestep slab
#define TSTEPS 8                  // timesteps per staged tile (1 KB DMA)
#define NBUF 4
#define NTILES (TL / TSTEPS)      // 256

typedef float v2f __attribute__((ext_vector_type(2)));

__device__ __forceinline__ float rcp_(float x)  { return __builtin_amdgcn_rcpf(x); }
__device__ __forceinline__ float exp2_(float x) { return __builtin_amdgcn_exp2f(x); }

// row_newbcast:K (DPP ctrl 0x150+K): every lane of each 16-lane row receives
// src from lane K of that row. old=0 + bound_ctrl=true + full masks -> old is
// provably unread -> folds to a SINGLE v_mov_b32_dpp.
template<int K> __device__ __forceinline__ float bcast16(float x) {
    return __int_as_float(__builtin_amdgcn_update_dpp(
        0, __float_as_int(x), 0x150 + K, 0xF, 0xF, true));
}

// v_pk_fma_f32 with explicit op_sel: guarantees ZERO splat movs (src1's lo
// word feeds both halves / hi word feeds both halves). R11-proven encodings.
// R15's builtin-splat form may materialize {x,x} pairs (~18 movs/step) if
// LLVM doesn't fold the splat shuffle into op_sel — this round measures that.
#define PK_FMA_LL(acc, w, x) asm("v_pk_fma_f32 %0, %1, %2, %0 op_sel_hi:[1,0,1]" \
                                 : "+v"(acc) : "v"(w), "v"(x))
#define PK_FMA_HH(acc, w, x) asm("v_pk_fma_f32 %0, %1, %2, %0 op_sel:[0,1,0] op_sel_hi:[1,1,1]" \
                                 : "+v"(acc) : "v"(w), "v"(x))
#define PK_ADD(d, a, b)      asm("v_pk_add_f32 %0, %1, %2" : "=v"(d) : "v"(a), "v"(b))

__device__ __forceinline__ void lstm_step(const float4& X0, const float4& X1,
        const v2f (&wx01)[INSZ], const v2f (&wx23)[INSZ],
        const v2f (&wh01)[HID], const v2f (&wh23)[HID],
        const v2f& b01, const v2f& b23, v2f& hd, float& hst, float& cst) {
    v2f a01e = b01, a23e = b23;
    v2f a01o = {0.f, 0.f}, a23o = {0.f, 0.f};
    const v2f xp0 = {X0.x, X0.y}, xp1 = {X0.z, X0.w};
    const v2f xp2 = {X1.x, X1.y}, xp3 = {X1.z, X1.w};
    // x-dot: 16 pk_fma, even input -> e-bank (lo of pair), odd -> o-bank (hi).
    PK_FMA_LL(a01e, wx01[0], xp0); PK_FMA_LL(a23e, wx23[0], xp0);
    PK_FMA_HH(a01o, wx01[1], xp0); PK_FMA_HH(a23o, wx23[1], xp0);
    PK_FMA_LL(a01e, wx01[2], xp1); PK_FMA_LL(a23e, wx23[2], xp1);
    PK_FMA_HH(a01o, wx01[3], xp1); PK_FMA_HH(a23o, wx23[3], xp1);
    PK_FMA_LL(a01e, wx01[4], xp2); PK_FMA_LL(a23e, wx23[4], xp2);
    PK_FMA_HH(a01o, wx01[5], xp2); PK_FMA_HH(a23o, wx23[5], xp2);
    PK_FMA_LL(a01e, wx01[6], xp3); PK_FMA_LL(a23e, wx23[6], xp3);
    PK_FMA_HH(a01o, wx01[7], xp3); PK_FMA_HH(a23o, wx23[7], xp3);
    // h-dot: 10 single-instr DPP broadcasts riding in hd.x (hd.y never read
    // under op_sel_hi:[1,0,1]; hd zero-initialized once per tile by caller).
#define HTERM(K, A01, A23) \
    hd.x = bcast16<K>(hst); \
    PK_FMA_LL(A01, wh01[K], hd); PK_FMA_LL(A23, wh23[K], hd)
    HTERM(0, a01e, a23e); HTERM(1, a01o, a23o);
    HTERM(2, a01e, a23e); HTERM(3, a01o, a23o);
    HTERM(4, a01e, a23e); HTERM(5, a01o, a23o);
    HTERM(6, a01e, a23e); HTERM(7, a01o, a23o);
    HTERM(8, a01e, a23e); HTERM(9, a01o, a23o);
#undef HTERM
    v2f a01, a23;
    PK_ADD(a01, a01e, a01o);
    PK_ADD(a23, a23e, a23o);
    // Batched reciprocal: ONE rcp serves all 4 gates (weights pre-scaled by
    // -log2e / -2log2e). Overflow-safe: each d <= ~2^25.
    const float d0 = 1.f + exp2_(a01.x);
    const float d1 = 1.f + exp2_(a01.y);
    const float d2 = 1.f + exp2_(a23.x);
    const float d3 = 1.f + exp2_(a23.y);
    const float p01 = d0 * d1, p23 = d2 * d3;
    const float r   = rcp_(p01 * p23);
    const float r01 = r * p23, r23 = r * p01;
    const float ig = r01 * d1;                    // 1/d0 = sigmoid(i)
    const float fg = r01 * d0;                    // 1/d1 = sigmoid(f)
    const float gg = fmaf(2.f, r23 * d3, -1.f);   // 2/d2-1 = tanh(g)
    const float og = r23 * d2;                    // 1/d3 = sigmoid(o)
    cst = fmaf(fg, cst, ig * gg);
    const float th = fmaf(2.f, rcp_(1.f + exp2_(cst * (-2.f * LOG2E))), -1.f);
    hst = og * th;
}

// One global_load_lds dwordx4: lane l's 16 B -> ldsbase + l*16 (wave-uniform
// base, linear lane layout). Consumers read through LDS (memory), so the
// "memory"-clobbered counted waits order them correctly (R7-proven).
__device__ __forceinline__ void stage_tile(const float* gsrc_lane, float* ldsbase) {
    __builtin_amdgcn_global_load_lds(
        (const __attribute__((address_space(1))) void*)(uintptr_t)gsrc_lane,
        (__attribute__((address_space(3))) void*)(uint32_t)(uintptr_t)ldsbase,
        16, 0, 0);
}

template<int VM>
__device__ __forceinline__ void consume_tile(const float (&xb)[TSTEPS][4][INSZ],
        int grp,
        const v2f (&wx01)[INSZ], const v2f (&wx23)[INSZ],
        const v2f (&wh01)[HID], const v2f (&wh23)[HID],
        const v2f& b01, const v2f& b23, float& hst, float& cst) {
    asm volatile("s_waitcnt vmcnt(%0)" :: "i"(VM) : "memory");
    v2f hd = {0.f, 0.f};   // pair register for DPP broadcasts (once per tile)
#pragma unroll
    for (int s = 0; s < TSTEPS; ++s) {
        const float4 xlo = *(const float4*)&xb[s][grp][0];
        const float4 xhi = *(const float4*)&xb[s][grp][4];
        lstm_step(xlo, xhi, wx01, wx23, wh01, wh23, b01, b23, hd, hst, cst);
    }
}

// 16 lanes per chain, 4 chains per wave, 1024 waves = 1 wave/SIMD.
// Lane j16<10 owns hidden unit j: gate rows {j,10+j,20+j,30+j}.
// h exchanged via DPP row_newbcast. x staged via 4-deep LDS DMA pipeline.
// waves_per_eu(1,1): max=1 disarms the occupancy-driven register squeeze
// (R14-proven: weights resident, VGPR 132).
__global__ void __attribute__((amdgpu_flat_work_group_size(64, 64)))
                __attribute__((amdgpu_waves_per_eu(1, 1)))
lstm_fused(
    const float* __restrict__ x,
    const float* __restrict__ h0,
    const float* __restrict__ c0,
    const float* __restrict__ Wih,
    const float* __restrict__ Whh,
    const float* __restrict__ bih,
    const float* __restrict__ bhh,
    const float* __restrict__ Wfc,
    const float* __restrict__ bfc,
    float* __restrict__ out)
{
    __shared__ float xbuf[NBUF][TSTEPS][4][INSZ];   // 4 KB

    const int lane = threadIdx.x;
    const int j16  = lane & 15;
    const int grp  = lane >> 4;
    const int n    = ((int)blockIdx.x << 2) + grp;
    const int j    = (j16 < HID) ? j16 : 0;   // clamp padding lanes
    const int src  = lane & 48;               // 16-lane group base

    const int ri = j, rf = HID + j, rg = 2 * HID + j, ro = 3 * HID + j;
    const float si = -LOG2E, sg = -2.f * LOG2E;

    // Weights as gate-pair float2s (76 regs), activation scale folded in.
    v2f wx01[INSZ], wx23[INSZ], wh01[HID], wh23[HID];
#pragma unroll
    for (int i = 0; i < INSZ; ++i) {
        wx01[i] = (v2f){Wih[ri * INSZ + i] * si, Wih[rf * INSZ + i] * si};
        wx23[i] = (v2f){Wih[rg * INSZ + i] * sg, Wih[ro * INSZ + i] * si};
    }
#pragma unroll
    for (int k = 0; k < HID; ++k) {
        wh01[k] = (v2f){Whh[ri * HID + k] * si, Whh[rf * HID + k] * si};
        wh23[k] = (v2f){Whh[rg * HID + k] * sg, Whh[ro * HID + k] * si};
    }
    const v2f b01 = (v2f){(bih[ri] + bhh[ri]) * si, (bih[rf] + bhh[rf]) * si};
    const v2f b23 = (v2f){(bih[rg] + bhh[rg]) * sg, (bih[ro] + bhh[ro]) * si};

    float cst = c0[n * HID + j];
    float hst = h0[n * HID + j];

    // Per-lane staging source: lane l covers (ts = l>>3, chain = (l>>1)&3,
    // half = l&1) -> LDS byte l*16 matches xbuf[..][ts][chain][half*4..+3].
    const int ts = lane >> 3, ch = (lane >> 1) & 3, hf = lane & 1;
    const float* gl = x + (size_t)ts * XS
                        + (size_t)((((int)blockIdx.x << 2) + ch) * INSZ + hf * 4);

    asm volatile("" ::: "memory");
#pragma unroll
    for (int b = 0; b < NBUF; ++b) {
        stage_tile(gl, &xbuf[b][0][0][0]);
        asm volatile("" ::: "memory");
        gl += (size_t)TSTEPS * XS;
    }

    // Main: counted vmcnt(3) completes exactly the oldest (this tile's) DMA;
    // lgkmcnt(0) ensures the buffer's ds_reads retired before its rewrite.
    for (int tile = 0; tile < NTILES - NBUF; ++tile) {
        const int b = tile & (NBUF - 1);
        consume_tile<3>(xbuf[b], grp, wx01, wx23, wh01, wh23, b01, b23, hst, cst);
        asm volatile("s_waitcnt lgkmcnt(0)" ::: "memory");
        stage_tile(gl, &xbuf[b][0][0][0]);
        asm volatile("" ::: "memory");
        gl += (size_t)TSTEPS * XS;
    }
    // Drain: descending counted waits, no reissue.
    consume_tile<3>(xbuf[0], grp, wx01, wx23, wh01, wh23, b01, b23, hst, cst);
    consume_tile<2>(xbuf[1], grp, wx01, wx23, wh01, wh23, b01, b23, hst, cst);
    consume_tile<1>(xbuf[2], grp, wx01, wx23, wh01, wh23, b01, b23, hst, cst);
    consume_tile<0>(xbuf[3], grp, wx01, wx23, wh01, wh23, b01, b23, hst, cst);

    // epilogue (one-time, DS shuffles fine here): y = h @ W_fc.T + b_fc; dump h, c
    float hv[HID];
#pragma unroll
    for (int k = 0; k < HID; ++k) hv[k] = __shfl(hst, src + k, 64);

    if (j16 < INSZ) {
        float acc = bfc[j16];
#pragma unroll
        for (int k = 0; k < HID; ++k) acc = fmaf(Wfc[j16 * HID + k], hv[k], acc);
        out[n * INSZ + j16] = acc;
    }
    if (j16 < HID) {
        out[NB * INSZ + n * HID + j16] = hst;
        out[NB * INSZ + NB * HID + n * HID + j16] = cst;
    }
}

extern "C" void kernel_launch(void* const* d_in, const int* in_sizes, int n_in,
                              void* d_out, int out_size, void* d_ws, size_t ws_size,
                              hipStream_t stream) {
    const float* x   = (const float*)d_in[0];
    const float* h0  = (const float*)d_in[1];
    const float* c0  = (const float*)d_in[2];
    const float* Wih = (const float*)d_in[3];
    const float* Whh = (const float*)d_in[4];
    const float* bih = (const float*)d_in[5];
    const float* bhh = (const float*)d_in[6];
    const float* Wfc = (const float*)d_in[7];
    const float* bfc = (const float*)d_in[8];
    float* out = (float*)d_out;

    lstm_fused<<<NB / 4, 64, 0, stream>>>(x, h0, c0, Wih, Whh, bih, bhh, Wfc, bfc, out);
}

// Round 17
// 358.426 us; speedup vs baseline: 1.1616x; 1.1616x over previous
//
#include <hip/hip_runtime.h>
#include <stdint.h>

#define TL  2048
#define NB  4096
#define INSZ 8
#define HID 10
#define LOG2E 1.4426950408889634f
#define XS (NB * INSZ)            // floats per timestep slab
#define TSTEPS 8                  // timesteps per staged tile (1 KB DMA)
#define NBUF 4
#define NTILES (TL / TSTEPS)      // 256

typedef float v2f __attribute__((ext_vector_type(2)));

__device__ __forceinline__ float rcp_(float x)  { return __builtin_amdgcn_rcpf(x); }
__device__ __forceinline__ float exp2_(float x) { return __builtin_amdgcn_exp2f(x); }

// row_newbcast:K (DPP ctrl 0x150+K): every lane of each 16-lane row receives
// src from lane K of that row. old=0 + bound_ctrl=true + full masks -> old is
// provably unread -> folds to a SINGLE v_mov_b32_dpp.
template<int K> __device__ __forceinline__ float bcast16(float x) {
    return __int_as_float(__builtin_amdgcn_update_dpp(
        0, __float_as_int(x), 0x150 + K, 0xF, 0xF, true));
}

// One LSTM step. K-PAIRED packed math: every v_pk_fma_f32 operand is a
// genuine register pair — x pairs alias float4 halves, h pairs are built by
// two DPP writes, accumulators are born from the first FMA with C={bias,0}.
// ZERO splat/init movs by construction (R15's {x,x} splat forms may have
// materialized movs; R16's asm fix broke scheduling — this keeps both).
// Weights pre-scaled by -log2e (i,f,o) / -2log2e (g); ONE batched rcp serves
// all 4 gate activations.
__device__ __forceinline__ void lstm_step(const float4& X0, const float4& X1,
        const v2f (&wxp)[4][4], const v2f (&whp)[4][5], const v2f (&bp)[4],
        float& hst, float& cst) {
    const v2f xp0 = {X0.x, X0.y}, xp1 = {X0.z, X0.w};
    const v2f xp2 = {X1.x, X1.y}, xp3 = {X1.z, X1.w};
    // x-dot: 16 pk_fma; accumulators start at {bias, 0} via the C operand.
    v2f a0 = __builtin_elementwise_fma(wxp[0][0], xp0, bp[0]);
    v2f a1 = __builtin_elementwise_fma(wxp[1][0], xp0, bp[1]);
    v2f a2 = __builtin_elementwise_fma(wxp[2][0], xp0, bp[2]);
    v2f a3 = __builtin_elementwise_fma(wxp[3][0], xp0, bp[3]);
    a0 = __builtin_elementwise_fma(wxp[0][1], xp1, a0);
    a1 = __builtin_elementwise_fma(wxp[1][1], xp1, a1);
    a2 = __builtin_elementwise_fma(wxp[2][1], xp1, a2);
    a3 = __builtin_elementwise_fma(wxp[3][1], xp1, a3);
    a0 = __builtin_elementwise_fma(wxp[0][2], xp2, a0);
    a1 = __builtin_elementwise_fma(wxp[1][2], xp2, a1);
    a2 = __builtin_elementwise_fma(wxp[2][2], xp2, a2);
    a3 = __builtin_elementwise_fma(wxp[3][2], xp2, a3);
    a0 = __builtin_elementwise_fma(wxp[0][3], xp3, a0);
    a1 = __builtin_elementwise_fma(wxp[1][3], xp3, a1);
    a2 = __builtin_elementwise_fma(wxp[2][3], xp3, a2);
    a3 = __builtin_elementwise_fma(wxp[3][3], xp3, a3);
    // h-dot: 5 k-pairs; each pair = 2 DPP writes + 4 pk_fma.
#define HPAIR(P) do { \
        v2f hp; \
        hp.x = bcast16<2 * (P)>(hst); \
        hp.y = bcast16<2 * (P) + 1>(hst); \
        a0 = __builtin_elementwise_fma(whp[0][P], hp, a0); \
        a1 = __builtin_elementwise_fma(whp[1][P], hp, a1); \
        a2 = __builtin_elementwise_fma(whp[2][P], hp, a2); \
        a3 = __builtin_elementwise_fma(whp[3][P], hp, a3); \
    } while (0)
    HPAIR(0); HPAIR(1); HPAIR(2); HPAIR(3); HPAIR(4);
#undef HPAIR
    // Horizontal adds (even/odd halves), then batched reciprocal:
    // r = 1/(d0 d1 d2 d3); overflow-safe (each d <= ~2^25).
    const float A0 = a0.x + a0.y;
    const float A1 = a1.x + a1.y;
    const float A2 = a2.x + a2.y;
    const float A3 = a3.x + a3.y;
    const float d0 = 1.f + exp2_(A0);
    const float d1 = 1.f + exp2_(A1);
    const float d2 = 1.f + exp2_(A2);
    const float d3 = 1.f + exp2_(A3);
    const float p01 = d0 * d1, p23 = d2 * d3;
    const float r   = rcp_(p01 * p23);
    const float r01 = r * p23, r23 = r * p01;
    const float ig = r01 * d1;                    // 1/d0 = sigmoid(i)
    const float fg = r01 * d0;                    // 1/d1 = sigmoid(f)
    const float gg = fmaf(2.f, r23 * d3, -1.f);   // 2/d2-1 = tanh(g)
    const float og = r23 * d2;                    // 1/d3 = sigmoid(o)
    cst = fmaf(fg, cst, ig * gg);
    const float th = fmaf(2.f, rcp_(1.f + exp2_(cst * (-2.f * LOG2E))), -1.f);
    hst = og * th;
}

// One global_load_lds dwordx4: lane l's 16 B -> ldsbase + l*16 (wave-uniform
// base, linear lane layout). Consumers read through LDS (memory), so the
// "memory"-clobbered counted waits order them correctly (R7-proven).
__device__ __forceinline__ void stage_tile(const float* gsrc_lane, float* ldsbase) {
    __builtin_amdgcn_global_load_lds(
        (const __attribute__((address_space(1))) void*)(uintptr_t)gsrc_lane,
        (__attribute__((address_space(3))) void*)(uint32_t)(uintptr_t)ldsbase,
        16, 0, 0);
}

template<int VM>
__device__ __forceinline__ void consume_tile(const float (&xb)[TSTEPS][4][INSZ],
        int grp, const v2f (&wxp)[4][4], const v2f (&whp)[4][5],
        const v2f (&bp)[4], float& hst, float& cst) {
    asm volatile("s_waitcnt vmcnt(%0)" :: "i"(VM) : "memory");
#pragma unroll
    for (int s = 0; s < TSTEPS; ++s) {
        const float4 xlo = *(const float4*)&xb[s][grp][0];
        const float4 xhi = *(const float4*)&xb[s][grp][4];
        lstm_step(xlo, xhi, wxp, whp, bp, hst, cst);
    }
}

// 16 lanes per chain, 4 chains per wave, 1024 waves = 1 wave/SIMD.
// Lane j16<10 owns hidden unit j: gate rows {j,10+j,20+j,30+j}.
// h exchanged via DPP row_newbcast. x staged via 4-deep LDS DMA pipeline.
// waves_per_eu(1,1): max=1 disarms the occupancy-driven register squeeze
// (R14-proven: weights resident, VGPR 132).
__global__ void __attribute__((amdgpu_flat_work_group_size(64, 64)))
                __attribute__((amdgpu_waves_per_eu(1, 1)))
lstm_fused(
    const float* __restrict__ x,
    const float* __restrict__ h0,
    const float* __restrict__ c0,
    const float* __restrict__ Wih,
    const float* __restrict__ Whh,
    const float* __restrict__ bih,
    const float* __restrict__ bhh,
    const float* __restrict__ Wfc,
    const float* __restrict__ bfc,
    float* __restrict__ out)
{
    __shared__ float xbuf[NBUF][TSTEPS][4][INSZ];   // 4 KB

    const int lane = threadIdx.x;
    const int j16  = lane & 15;
    const int grp  = lane >> 4;
    const int n    = ((int)blockIdx.x << 2) + grp;
    const int j    = (j16 < HID) ? j16 : 0;   // clamp padding lanes
    const int src  = lane & 48;               // 16-lane group base

    // Weights as K-pair float2s (76 regs), activation scale folded in.
    // wxp[g][p] = {Wih[row_g][2p], Wih[row_g][2p+1]} * s_g
    // whp[g][p] = {Whh[row_g][2p], Whh[row_g][2p+1]} * s_g
    v2f wxp[4][4], whp[4][5], bp[4];
#pragma unroll
    for (int g = 0; g < 4; ++g) {
        const int row = g * HID + j;
        const float s = (g == 2 ? -2.f : -1.f) * LOG2E;
#pragma unroll
        for (int p = 0; p < 4; ++p)
            wxp[g][p] = (v2f){Wih[row * INSZ + 2 * p] * s,
                              Wih[row * INSZ + 2 * p + 1] * s};
#pragma unroll
        for (int p = 0; p < 5; ++p)
            whp[g][p] = (v2f){Whh[row * HID + 2 * p] * s,
                              Whh[row * HID + 2 * p + 1] * s};
        bp[g] = (v2f){(bih[row] + bhh[row]) * s, 0.f};
    }

    float cst = c0[n * HID + j];
    float hst = h0[n * HID + j];

    // Per-lane staging source: lane l covers (ts = l>>3, chain = (l>>1)&3,
    // half = l&1) -> LDS byte l*16 matches xbuf[..][ts][chain][half*4..+3].
    const int ts = lane >> 3, ch = (lane >> 1) & 3, hf = lane & 1;
    const float* gl = x + (size_t)ts * XS
                        + (size_t)((((int)blockIdx.x << 2) + ch) * INSZ + hf * 4);

    asm volatile("" ::: "memory");
#pragma unroll
    for (int b = 0; b < NBUF; ++b) {
        stage_tile(gl, &xbuf[b][0][0][0]);
        asm volatile("" ::: "memory");
        gl += (size_t)TSTEPS * XS;
    }

    // Main: counted vmcnt(3) completes exactly the oldest (this tile's) DMA;
    // lgkmcnt(0) ensures the buffer's ds_reads retired before its rewrite.
    for (int tile = 0; tile < NTILES - NBUF; ++tile) {
        const int b = tile & (NBUF - 1);
        consume_tile<3>(xbuf[b], grp, wxp, whp, bp, hst, cst);
        asm volatile("s_waitcnt lgkmcnt(0)" ::: "memory");
        stage_tile(gl, &xbuf[b][0][0][0]);
        asm volatile("" ::: "memory");
        gl += (size_t)TSTEPS * XS;
    }
    // Drain: descending counted waits, no reissue.
    consume_tile<3>(xbuf[0], grp, wxp, whp, bp, hst, cst);
    consume_tile<2>(xbuf[1], grp, wxp, whp, bp, hst, cst);
    consume_tile<1>(xbuf[2], grp, wxp, whp, bp, hst, cst);
    consume_tile<0>(xbuf[3], grp, wxp, whp, bp, hst, cst);

    // epilogue (one-time, DS shuffles fine here): y = h @ W_fc.T + b_fc; dump h, c
    float hv[HID];
#pragma unroll
    for (int k = 0; k < HID; ++k) hv[k] = __shfl(hst, src + k, 64);

    if (j16 < INSZ) {
        float acc = bfc[j16];
#pragma unroll
        for (int k = 0; k < HID; ++k) acc = fmaf(Wfc[j16 * HID + k], hv[k], acc);
        out[n * INSZ + j16] = acc;
    }
    if (j16 < HID) {
        out[NB * INSZ + n * HID + j16] = hst;
        out[NB * INSZ + NB * HID + n * HID + j16] = cst;
    }
}

extern "C" void kernel_launch(void* const* d_in, const int* in_sizes, int n_in,
                              void* d_out, int out_size, void* d_ws, size_t ws_size,
                              hipStream_t stream) {
    const float* x   = (const float*)d_in[0];
    const float* h0  = (const float*)d_in[1];
    const float* c0  = (const float*)d_in[2];
    const float* Wih = (const float*)d_in[3];
    const float* Whh = (const float*)d_in[4];
    const float* bih = (const float*)d_in[5];
    const float* bhh = (const float*)d_in[6];
    const float* Wfc = (const float*)d_in[7];
    const float* bfc = (const float*)d_in[8];
    float* out = (float*)d_out;

    lstm_fused<<<NB / 4, 64, 0, stream>>>(x, h0, c0, Wih, Whh, bih, bhh, Wfc, bfc, out);
}